// Round 5
// baseline (1310.246 us; speedup 1.0000x reference)
//
#include <hip/hip_runtime.h>
#include <float.h>
#include <math.h>
#include <stdint.h>

#define T_ 1024
#define D_ 1024
#define H_ 16
#define HD_ 64
#define E_ 8
#define F_ 2560
#define D3_ 3072
#define F2_ 5120

// ---- workspace layout (float offsets) ----
// WS_H..WS_ATTN region is reused late as 4 split-K partial buffers (16 MB).
#define WS_H    0u         // 1M   LN1 out / attn sacc / moe partials[0]
#define WS_QKV  1048576u   // 3M   qkv (T,3D) / moe partials[1..3]
#define WS_ATTN 4194304u   // 1M   attention out (T,D)
#define WS_X2   5242880u   // 1M   x + attn proj (T,D)
#define WS_H2   6291456u   // 1M   LN2 out
#define WS_A    7340032u   // 2.62M gated activation (T,F)
#define WS_GW   9961472u
#define WS_GI   9962496u
#define WS_OFFS 9963520u
#define WS_PERM 9963536u
#define WS_PART 0u         // 4 * T_*D_ floats = 16 MB (overlaps WS_H+WS_QKV)

typedef short short8 __attribute__((ext_vector_type(8)));
typedef __bf16 bf16x8 __attribute__((ext_vector_type(8)));
typedef float floatx4 __attribute__((ext_vector_type(4)));

union FragU { short8 s; bf16x8 b; };

__device__ __forceinline__ short f2bf(float f) {
    union { float f; uint32_t u; } a; a.f = f;
    uint32_t r = a.u + 0x7fffu + ((a.u >> 16) & 1u);
    return (short)(r >> 16);
}

__device__ __forceinline__ void cvt16(const float4& a0, const float4& a1,
                                      const float4& a2, const float4& a3,
                                      short8& c0, short8& c1) {
    c0[0]=f2bf(a0.x); c0[1]=f2bf(a0.y); c0[2]=f2bf(a0.z); c0[3]=f2bf(a0.w);
    c0[4]=f2bf(a1.x); c0[5]=f2bf(a1.y); c0[6]=f2bf(a1.z); c0[7]=f2bf(a1.w);
    c1[0]=f2bf(a2.x); c1[1]=f2bf(a2.y); c1[2]=f2bf(a2.z); c1[3]=f2bf(a2.w);
    c1[4]=f2bf(a3.x); c1[5]=f2bf(a3.y); c1[6]=f2bf(a3.z); c1[7]=f2bf(a3.w);
}

// build B-frag from fp32 activation row (k-contiguous)
__device__ __forceinline__ void bfrag(const float* p, FragU& f) {
    float4 f0 = *(const float4*)p;
    float4 f1 = *(const float4*)(p + 4);
    f.s[0]=f2bf(f0.x); f.s[1]=f2bf(f0.y); f.s[2]=f2bf(f0.z); f.s[3]=f2bf(f0.w);
    f.s[4]=f2bf(f1.x); f.s[5]=f2bf(f1.y); f.s[6]=f2bf(f1.z); f.s[7]=f2bf(f1.w);
}

// ===================== swapped-operand TN GEMMs =====================
// C^T = W^T @ act^T.  W fp32 [K][Mtot] streamed coalesced row-wise into
// frag-layout LDS (bf16, k-pair packed b32 writes). act fp32 [tok][K] loaded
// direct global->register as B-frags (k-contiguous). BM=64 (out cols),
// BN=128 (tokens), BK=32. 4 waves: wm(m half 32) x wn(tok half 64).
// C/D: lane&15 -> token, (lane>>4)*4+reg -> out-col. LDS-transpose epilogue.

#define SW_IDS \
    const int tid = threadIdx.x;                   \
    const int lane = tid & 63, wave = tid >> 6;    \
    const int wm = wave & 1, wn = wave >> 1;       \
    const int quad = lane >> 4, lm = lane & 15;    \
    const int krp = tid >> 4, mseg = tid & 15;     \
    const int kc_w = krp >> 2, jd = krp & 3;

#define SW_PACK(P0, P1, AU) {                                              \
    _Pragma("unroll")                                                      \
    for (int c = 0; c < 4; c++) {                                          \
        uint32_t v = (uint32_t)(unsigned short)f2bf(((const float*)&P0)[c])\
              | ((uint32_t)(unsigned short)f2bf(((const float*)&P1)[c]) << 16); \
        AU[(kc_w*64 + mseg*4 + c)*4 + jd] = v;                             \
    } }

// ---- qkv projection: qkv[tok][3072] = h @ qkvw + qkvb ----
__global__ __launch_bounds__(256) void qkv_sw(
    const float* __restrict__ h, const float* __restrict__ qkvw,
    const float* __restrict__ qkvb, float* __restrict__ qkv)
{
    const int n0 = blockIdx.x * 128;   // token tile
    const int m0 = blockIdx.y * 64;    // out-col tile

    __shared__ __align__(16) short As[4*64*8];
    __shared__ __align__(16) float Ct[128*68];
    SW_IDS

    int btok[4];
    #pragma unroll
    for (int j = 0; j < 4; j++) btok[j] = n0 + wn*64 + j*16 + lm;

    floatx4 acc[2][4];
    #pragma unroll
    for (int i=0;i<2;i++)
        #pragma unroll
        for (int j=0;j<4;j++) acc[i][j] = (floatx4){0.f,0.f,0.f,0.f};

    const float* Wb = qkvw + (size_t)(2*krp)*D3_ + m0 + mseg*4;
    float4 p0 = *(const float4*)(Wb);
    float4 p1 = *(const float4*)(Wb + D3_);

    for (int k0 = 0; k0 < D_; k0 += 32) {
        __syncthreads();
        uint32_t* Au = (uint32_t*)As;
        SW_PACK(p0, p1, Au)
        __syncthreads();
        if (k0 + 32 < D_) {
            const float* Wn = Wb + (size_t)(k0+32)*D3_;
            p0 = *(const float4*)(Wn);
            p1 = *(const float4*)(Wn + D3_);
        }
        FragU fb[4];
        #pragma unroll
        for (int j = 0; j < 4; j++)
            bfrag(h + (size_t)btok[j]*D_ + k0 + quad*8, fb[j]);
        FragU fa[2];
        #pragma unroll
        for (int i = 0; i < 2; i++)
            fa[i].s = *(short8*)&As[(quad*64 + wm*32 + i*16 + lm)*8];
        #pragma unroll
        for (int i = 0; i < 2; i++)
            #pragma unroll
            for (int j = 0; j < 4; j++)
                acc[i][j] = __builtin_amdgcn_mfma_f32_16x16x32_bf16(fa[i].b, fb[j].b, acc[i][j], 0,0,0);
    }
    #pragma unroll
    for (int i = 0; i < 2; i++)
        #pragma unroll
        for (int r = 0; r < 4; r++) {
            int colL = wm*32 + i*16 + quad*4 + r;
            float bb = qkvb[m0 + colL];
            #pragma unroll
            for (int j = 0; j < 4; j++)
                Ct[(wn*64 + j*16 + lm)*68 + colL] = acc[i][j][r] + bb;
        }
    __syncthreads();
    {
        int row = tid >> 1, half = tid & 1;
        float* op = qkv + (size_t)(n0 + row)*D3_ + m0 + half*32;
        const float* cp = &Ct[row*68 + half*32];
        #pragma unroll
        for (int i = 0; i < 8; i++)
            *(float4*)(op + i*4) = *(const float4*)(cp + i*4);
    }
}

// ---- MoE fc + GLU: aout[tok][F] = x1 * gelu(x2), routed ----
__global__ __launch_bounds__(256) void moe_fc_sw(
    const float* __restrict__ h2, const float* __restrict__ fcw,
    const float* __restrict__ fcb, const int* __restrict__ offs,
    const int* __restrict__ perm, float* __restrict__ aout)
{
    const int e = blockIdx.z;
    const int off = offs[e], Ne = offs[e+1] - off;
    const int n0 = blockIdx.x * 128;
    if (n0 >= Ne) return;
    const int m0 = blockIdx.y * 64;

    __shared__ __align__(16) short As1[4*64*8];
    __shared__ __align__(16) short As2[4*64*8];
    __shared__ __align__(16) float Ct[128*68];
    __shared__ int toks[128];
    SW_IDS

    if (tid < 128) {
        int r = n0 + tid;
        toks[tid] = (r < Ne) ? perm[off + r] : -1;
    }
    __syncthreads();

    int btok[4];
    #pragma unroll
    for (int j = 0; j < 4; j++) btok[j] = toks[wn*64 + j*16 + lm];

    floatx4 acc1[2][4], acc2[2][4];
    #pragma unroll
    for (int i=0;i<2;i++)
        #pragma unroll
        for (int j=0;j<4;j++) {
            acc1[i][j] = (floatx4){0.f,0.f,0.f,0.f};
            acc2[i][j] = (floatx4){0.f,0.f,0.f,0.f};
        }

    const float* W1 = fcw + (size_t)e*D_*F2_ + (size_t)(2*krp)*F2_ + m0 + mseg*4;
    const float* W2 = W1 + F_;
    float4 p10 = *(const float4*)(W1);
    float4 p11 = *(const float4*)(W1 + F2_);
    float4 p20 = *(const float4*)(W2);
    float4 p21 = *(const float4*)(W2 + F2_);

    for (int k0 = 0; k0 < D_; k0 += 32) {
        __syncthreads();
        uint32_t* A1u = (uint32_t*)As1;
        uint32_t* A2u = (uint32_t*)As2;
        SW_PACK(p10, p11, A1u)
        SW_PACK(p20, p21, A2u)
        __syncthreads();
        if (k0 + 32 < D_) {
            const float* W1n = W1 + (size_t)(k0+32)*F2_;
            p10 = *(const float4*)(W1n);
            p11 = *(const float4*)(W1n + F2_);
            const float* W2n = W2 + (size_t)(k0+32)*F2_;
            p20 = *(const float4*)(W2n);
            p21 = *(const float4*)(W2n + F2_);
        }
        FragU fb[4];
        #pragma unroll
        for (int j = 0; j < 4; j++) {
            if (btok[j] >= 0)
                bfrag(h2 + (size_t)btok[j]*D_ + k0 + quad*8, fb[j]);
            else
                fb[j].s = (short8){0,0,0,0,0,0,0,0};
        }
        FragU fa1[2], fa2[2];
        #pragma unroll
        for (int i = 0; i < 2; i++) {
            fa1[i].s = *(short8*)&As1[(quad*64 + wm*32 + i*16 + lm)*8];
            fa2[i].s = *(short8*)&As2[(quad*64 + wm*32 + i*16 + lm)*8];
        }
        #pragma unroll
        for (int i = 0; i < 2; i++)
            #pragma unroll
            for (int j = 0; j < 4; j++) {
                acc1[i][j] = __builtin_amdgcn_mfma_f32_16x16x32_bf16(fa1[i].b, fb[j].b, acc1[i][j], 0,0,0);
                acc2[i][j] = __builtin_amdgcn_mfma_f32_16x16x32_bf16(fa2[i].b, fb[j].b, acc2[i][j], 0,0,0);
            }
    }
    #pragma unroll
    for (int i = 0; i < 2; i++)
        #pragma unroll
        for (int r = 0; r < 4; r++) {
            int colL = wm*32 + i*16 + quad*4 + r;
            float b1 = fcb[(size_t)e*F2_ + m0 + colL];
            float b2 = fcb[(size_t)e*F2_ + F_ + m0 + colL];
            #pragma unroll
            for (int j = 0; j < 4; j++) {
                float v1 = acc1[i][j][r] + b1;
                float v2 = acc2[i][j][r] + b2;
                float g = v2 * 0.5f * (1.0f + erff(v2 * 0.70710678118654752f));
                Ct[(wn*64 + j*16 + lm)*68 + colL] = v1 * g;
            }
        }
    __syncthreads();
    {
        int row = tid >> 1, half = tid & 1;
        int tk = toks[row];
        if (tk >= 0) {
            float* op = aout + (size_t)tk*F_ + m0 + half*32;
            const float* cp = &Ct[row*68 + half*32];
            #pragma unroll
            for (int i = 0; i < 8; i++)
                *(float4*)(op + i*4) = *(const float4*)(cp + i*4);
        }
    }
}

// ---- MoE out, split-K=4 into disjoint partial buffers (no atomics) ----
__global__ __launch_bounds__(256) void moe_out_sw(
    const float* __restrict__ abuf, const float* __restrict__ ew,
    const int* __restrict__ offs, const int* __restrict__ perm,
    float* __restrict__ part)
{
    const int e = blockIdx.z >> 2;
    const int sk = blockIdx.z & 3;
    const int off = offs[e], Ne = offs[e+1] - off;
    const int n0 = blockIdx.x * 128;
    if (n0 >= Ne) return;
    const int m0 = blockIdx.y * 64;

    __shared__ __align__(16) short As[4*64*8];
    __shared__ __align__(16) float Ct[128*68];
    __shared__ int toks[128];
    SW_IDS

    if (tid < 128) {
        int r = n0 + tid;
        toks[tid] = (r < Ne) ? perm[off + r] : -1;
    }
    __syncthreads();

    int btok[4];
    #pragma unroll
    for (int j = 0; j < 4; j++) btok[j] = toks[wn*64 + j*16 + lm];

    floatx4 acc[2][4];
    #pragma unroll
    for (int i=0;i<2;i++)
        #pragma unroll
        for (int j=0;j<4;j++) acc[i][j] = (floatx4){0.f,0.f,0.f,0.f};

    const int koff = sk * (F_ / 4);           // 640
    const int kend = koff + (F_ / 4);
    const float* Wb = ew + (size_t)e*F_*D_ + (size_t)(koff + 2*krp)*D_ + m0 + mseg*4;
    float4 p0 = *(const float4*)(Wb);
    float4 p1 = *(const float4*)(Wb + D_);

    for (int k0 = koff; k0 < kend; k0 += 32) {
        __syncthreads();
        uint32_t* Au = (uint32_t*)As;
        SW_PACK(p0, p1, Au)
        __syncthreads();
        if (k0 + 32 < kend) {
            const float* Wn = Wb + (size_t)(k0 + 32 - koff)*D_;
            p0 = *(const float4*)(Wn);
            p1 = *(const float4*)(Wn + D_);
        }
        FragU fb[4];
        #pragma unroll
        for (int j = 0; j < 4; j++) {
            if (btok[j] >= 0)
                bfrag(abuf + (size_t)btok[j]*F_ + k0 + quad*8, fb[j]);
            else
                fb[j].s = (short8){0,0,0,0,0,0,0,0};
        }
        FragU fa[2];
        #pragma unroll
        for (int i = 0; i < 2; i++)
            fa[i].s = *(short8*)&As[(quad*64 + wm*32 + i*16 + lm)*8];
        #pragma unroll
        for (int i = 0; i < 2; i++)
            #pragma unroll
            for (int j = 0; j < 4; j++)
                acc[i][j] = __builtin_amdgcn_mfma_f32_16x16x32_bf16(fa[i].b, fb[j].b, acc[i][j], 0,0,0);
    }
    #pragma unroll
    for (int i = 0; i < 2; i++)
        #pragma unroll
        for (int r = 0; r < 4; r++) {
            int colL = wm*32 + i*16 + quad*4 + r;
            #pragma unroll
            for (int j = 0; j < 4; j++)
                Ct[(wn*64 + j*16 + lm)*68 + colL] = acc[i][j][r];
        }
    __syncthreads();
    {
        int row = tid >> 1, half = tid & 1;
        int tk = toks[row];
        if (tk >= 0) {
            float* op = part + (size_t)sk*T_*D_ + (size_t)tk*D_ + m0 + half*32;
            const float* cp = &Ct[row*68 + half*32];
            #pragma unroll
            for (int i = 0; i < 8; i++)
                *(float4*)(op + i*4) = *(const float4*)(cp + i*4);
        }
    }
}

// ===================== attn-out projection (round-4 kernel, kept) =====================
#define GEMM_IDS \
    const int tid  = threadIdx.x;                 \
    const int a_m  = tid >> 1;                    \
    const int a_kh = (tid & 1) * 16;              \
    const int lane = tid & 63, wave = tid >> 6;   \
    const int wm = wave & 1,  wn = wave >> 1;     \
    const int quad = lane >> 4, lm = lane & 15;

__global__ __launch_bounds__(256) void gemm_mfma_acc(
    const float* __restrict__ A, int lda,
    const float* __restrict__ B, int ldb,
    float* __restrict__ Cacc, int ldc, int K, int nsk)
{
    const int sk = blockIdx.z;
    const int row0 = blockIdx.y * 128;
    const int col0 = blockIdx.x * 64;

    __shared__ __align__(16) short As[4*128*8];
    __shared__ __align__(16) short Bs[64*40];
    GEMM_IDS
    const int b_n = tid >> 2, b_kc = tid & 3;

    floatx4 acc[4][2];
    #pragma unroll
    for (int i=0;i<4;i++)
        #pragma unroll
        for (int j=0;j<2;j++) acc[i][j] = (floatx4){0.f,0.f,0.f,0.f};

    const float* apx = A + (size_t)(row0 + a_m) * lda + a_kh;
    const float* bpx = B + (size_t)(b_kc*8) * ldb + col0 + b_n;
    const int kcA = (tid & 1) * 2;
    const int Kp = K / nsk;
    const int koff = sk * Kp, kend = koff + Kp;

    float4 a0, a1, a2, a3; float bvv[8];
    a0 = *(const float4*)(apx + koff);     a1 = *(const float4*)(apx + koff + 4);
    a2 = *(const float4*)(apx + koff + 8); a3 = *(const float4*)(apx + koff + 12);
    {
        const float* bp2 = bpx + (size_t)koff * ldb;
        #pragma unroll
        for (int j=0;j<8;j++) bvv[j] = bp2[(size_t)j*ldb];
    }

    for (int k0 = koff; k0 < kend; k0 += 32) {
        __syncthreads();
        short8 c0, c1, cb;
        cvt16(a0,a1,a2,a3,c0,c1);
        #pragma unroll
        for (int j=0;j<8;j++) cb[j] = f2bf(bvv[j]);
        *(short8*)&As[((kcA  )*128 + a_m)*8] = c0;
        *(short8*)&As[((kcA+1)*128 + a_m)*8] = c1;
        *(short8*)&Bs[b_n*40 + b_kc*8] = cb;
        __syncthreads();
        if (k0 + 32 < kend) {
            const float* ap2 = apx + k0 + 32;
            a0 = *(const float4*)(ap2);     a1 = *(const float4*)(ap2 + 4);
            a2 = *(const float4*)(ap2 + 8); a3 = *(const float4*)(ap2 + 12);
            const float* bp2 = bpx + (size_t)(k0+32) * ldb;
            #pragma unroll
            for (int j=0;j<8;j++) bvv[j] = bp2[(size_t)j*ldb];
        }
        FragU fa[4], fb[2];
        #pragma unroll
        for (int i=0;i<4;i++) fa[i].s = *(short8*)&As[(quad*128 + wm*64 + i*16 + lm)*8];
        #pragma unroll
        for (int j=0;j<2;j++) fb[j].s = *(short8*)&Bs[(wn*32 + j*16 + lm)*40 + quad*8];
        #pragma unroll
        for (int i=0;i<4;i++)
            #pragma unroll
            for (int j=0;j<2;j++)
                acc[i][j] = __builtin_amdgcn_mfma_f32_16x16x32_bf16(fa[i].b, fb[j].b, acc[i][j], 0,0,0);
    }
    #pragma unroll
    for (int i=0;i<4;i++)
        #pragma unroll
        for (int j=0;j<2;j++) {
            int col = col0 + wn*32 + j*16 + lm;
            #pragma unroll
            for (int r=0;r<4;r++) {
                int row = row0 + wm*64 + i*16 + quad*4 + r;
                atomicAdd(&Cacc[(size_t)row*ldc + col], acc[i][j][r]);
            }
        }
}

// ===================== MFMA flash attention (unchanged) =====================
__global__ __launch_bounds__(128) void flash_attn(
    const float* __restrict__ qkv, const int* __restrict__ ids,
    float* __restrict__ attnout)
{
    const int h  = blockIdx.y;
    const int q0 = blockIdx.x * 32;
    const int tid = threadIdx.x;
    const int lane = tid & 63, w = tid >> 6;
    const int quad = lane >> 4, lm = lane & 15;

    __shared__ __align__(16) short Qs[32*72];
    __shared__ __align__(16) short Ks[64*72];
    __shared__ __align__(16) short Vt[64*72];
    __shared__ __align__(16) short Ps[2][16*72];
    __shared__ int globf[32];

    {
        int row = tid >> 2, c = (tid & 3) * 16;
        const float* qp = qkv + (size_t)(q0 + row) * D3_ + h * HD_ + c;
        float4 f0 = *(const float4*)(qp);
        float4 f1 = *(const float4*)(qp + 4);
        float4 f2 = *(const float4*)(qp + 8);
        float4 f3 = *(const float4*)(qp + 12);
        short8 s0, s1;
        cvt16(f0, f1, f2, f3, s0, s1);
        *(short8*)&Qs[row*72 + c]     = s0;
        *(short8*)&Qs[row*72 + c + 8] = s1;
    }
    if (tid < 32) {
        int id = ids[q0 + tid];
        globf[tid] = (id >= 2 && id <= 7) ? 1 : 0;
    }
    __syncthreads();

    FragU QA[2];
    #pragma unroll
    for (int s = 0; s < 2; s++)
        QA[s].s = *(short8*)&Qs[(w*16 + lm)*72 + s*32 + quad*8];

    int any = 0;
    #pragma unroll
    for (int i = 0; i < 32; i++) any |= globf[i];
    const int nt = any ? (T_/64) : ((q0 + 31) >> 6) + 1;

    int gq[4]; int qidx[4];
    #pragma unroll
    for (int r = 0; r < 4; r++) {
        int ql = w*16 + quad*4 + r;
        qidx[r] = q0 + ql;
        gq[r] = globf[ql];
    }

    float mrow[4] = {-1e30f, -1e30f, -1e30f, -1e30f};
    float lrow[4] = {0.f, 0.f, 0.f, 0.f};
    floatx4 Oacc[4];
    #pragma unroll
    for (int n = 0; n < 4; n++) Oacc[n] = (floatx4){0.f, 0.f, 0.f, 0.f};

    for (int kt = 0; kt < nt; kt++) {
        __syncthreads();
        #pragma unroll
        for (int rep = 0; rep < 2; rep++) {
            int key = (tid >> 2) + rep*32;
            int c = (tid & 3) * 16;
            const float* kp = qkv + (size_t)(kt*64 + key) * D3_ + D_ + h*HD_ + c;
            float4 f0 = *(const float4*)(kp);
            float4 f1 = *(const float4*)(kp + 4);
            float4 f2 = *(const float4*)(kp + 8);
            float4 f3 = *(const float4*)(kp + 12);
            short8 s0, s1;
            cvt16(f0, f1, f2, f3, s0, s1);
            *(short8*)&Ks[key*72 + c]     = s0;
            *(short8*)&Ks[key*72 + c + 8] = s1;
        }
        #pragma unroll
        for (int rep = 0; rep < 8; rep++) {
            int lin = tid + rep*128;
            int key = lin >> 4;
            int c = (lin & 15) * 4;
            const float* vp = qkv + (size_t)(kt*64 + key) * D3_ + 2*D_ + h*HD_ + c;
            float4 f = *(const float4*)vp;
            Vt[(c+0)*72 + key] = f2bf(f.x);
            Vt[(c+1)*72 + key] = f2bf(f.y);
            Vt[(c+2)*72 + key] = f2bf(f.z);
            Vt[(c+3)*72 + key] = f2bf(f.w);
        }
        __syncthreads();

        floatx4 Sv[4];
        #pragma unroll
        for (int n = 0; n < 4; n++) {
            Sv[n] = (floatx4){0.f, 0.f, 0.f, 0.f};
            #pragma unroll
            for (int s = 0; s < 2; s++) {
                FragU KB;
                KB.s = *(short8*)&Ks[(n*16 + lm)*72 + s*32 + quad*8];
                Sv[n] = __builtin_amdgcn_mfma_f32_16x16x32_bf16(QA[s].b, KB.b, Sv[n], 0, 0, 0);
            }
        }
        #pragma unroll
        for (int n = 0; n < 4; n++) {
            int key = kt*64 + n*16 + lm;
            #pragma unroll
            for (int r = 0; r < 4; r++) {
                float v = Sv[n][r] * 0.125f;
                if (!gq[r] && key > qidx[r]) v = -1e30f;
                Sv[n][r] = v;
            }
        }
        float mnew[4], alpha[4], tsum[4];
        #pragma unroll
        for (int r = 0; r < 4; r++) {
            float tm = fmaxf(fmaxf(Sv[0][r], Sv[1][r]), fmaxf(Sv[2][r], Sv[3][r]));
            #pragma unroll
            for (int x = 1; x < 16; x <<= 1) tm = fmaxf(tm, __shfl_xor(tm, x));
            mnew[r] = fmaxf(mrow[r], tm);
            alpha[r] = __expf(mrow[r] - mnew[r]);
            mrow[r] = mnew[r];
            tsum[r] = 0.f;
        }
        #pragma unroll
        for (int n = 0; n < 4; n++) {
            #pragma unroll
            for (int r = 0; r < 4; r++) {
                float p = __expf(Sv[n][r] - mnew[r]);
                tsum[r] += p;
                Ps[w][(quad*4 + r)*72 + n*16 + lm] = f2bf(p);
            }
        }
        #pragma unroll
        for (int r = 0; r < 4; r++) {
            #pragma unroll
            for (int x = 1; x < 16; x <<= 1) tsum[r] += __shfl_xor(tsum[r], x);
            lrow[r] = lrow[r] * alpha[r] + tsum[r];
        }
        #pragma unroll
        for (int n = 0; n < 4; n++)
            #pragma unroll
            for (int r = 0; r < 4; r++) Oacc[n][r] *= alpha[r];

        #pragma unroll
        for (int s = 0; s < 2; s++) {
            FragU PA;
            PA.s = *(short8*)&Ps[w][lm*72 + s*32 + quad*8];
            #pragma unroll
            for (int n = 0; n < 4; n++) {
                FragU VB;
                VB.s = *(short8*)&Vt[(n*16 + lm)*72 + s*32 + quad*8];
                Oacc[n] = __builtin_amdgcn_mfma_f32_16x16x32_bf16(PA.b, VB.b, Oacc[n], 0, 0, 0);
            }
        }
    }

    #pragma unroll
    for (int n = 0; n < 4; n++)
        #pragma unroll
        for (int r = 0; r < 4; r++) {
            float o = Oacc[n][r] / lrow[r];
            attnout[(size_t)qidx[r]*D_ + h*HD_ + n*16 + lm] = o;
        }
}

// ===================== epilogues =====================
__global__ __launch_bounds__(256) void ep_attn(
    const float* __restrict__ x, const float* __restrict__ sacc,
    const float* __restrict__ aob, float* __restrict__ x2)
{
    int row = blockIdx.x, tid = threadIdx.x;
    float4 xv = ((const float4*)(x + (size_t)row*D_))[tid];
    float4 sv = ((const float4*)(sacc + (size_t)row*D_))[tid];
    float4 bv = ((const float4*)aob)[tid];
    float4 o;
    o.x = xv.x + sv.x + bv.x; o.y = xv.y + sv.y + bv.y;
    o.z = xv.z + sv.z + bv.z; o.w = xv.w + sv.w + bv.w;
    ((float4*)(x2 + (size_t)row*D_))[tid] = o;
}

__global__ __launch_bounds__(256) void ep_moe2(
    const float* __restrict__ x2, const float* __restrict__ part,
    const float* __restrict__ eob, const float* __restrict__ gw,
    const int* __restrict__ gi, float* __restrict__ out)
{
    int row = blockIdx.x, tid = threadIdx.x;
    float g = gw[row];
    int e = gi[row];
    float4 xv = ((const float4*)(x2 + (size_t)row*D_))[tid];
    float4 s0 = ((const float4*)(part + 0ul*T_*D_ + (size_t)row*D_))[tid];
    float4 s1 = ((const float4*)(part + 1ul*T_*D_ + (size_t)row*D_))[tid];
    float4 s2 = ((const float4*)(part + 2ul*T_*D_ + (size_t)row*D_))[tid];
    float4 s3 = ((const float4*)(part + 3ul*T_*D_ + (size_t)row*D_))[tid];
    float4 bv = ((const float4*)(eob + (size_t)e*D_))[tid];
    float4 o;
    o.x = xv.x + g*(s0.x+s1.x+s2.x+s3.x + bv.x);
    o.y = xv.y + g*(s0.y+s1.y+s2.y+s3.y + bv.y);
    o.z = xv.z + g*(s0.z+s1.z+s2.z+s3.z + bv.z);
    o.w = xv.w + g*(s0.w+s1.w+s2.w+s3.w + bv.w);
    ((float4*)(out + (size_t)row*D_))[tid] = o;
}

// ===================== small kernels =====================
__global__ __launch_bounds__(256) void ln_kernel(
    const float* __restrict__ x, const float* __restrict__ w,
    const float* __restrict__ b, float* __restrict__ out)
{
    const int row = blockIdx.x, tid = threadIdx.x;
    const int lane = tid & 63, wave = tid >> 6;
    float4 v = ((const float4*)(x + (size_t)row * D_))[tid];
    float s  = v.x + v.y + v.z + v.w;
    float sq = v.x*v.x + v.y*v.y + v.z*v.z + v.w*v.w;
    #pragma unroll
    for (int off = 32; off; off >>= 1) {
        s  += __shfl_down(s, off);
        sq += __shfl_down(sq, off);
    }
    __shared__ float rs[4], rq[4], mv[2];
    if (lane == 0) { rs[wave] = s; rq[wave] = sq; }
    __syncthreads();
    if (tid == 0) {
        float ts = rs[0]+rs[1]+rs[2]+rs[3];
        float tq = rq[0]+rq[1]+rq[2]+rq[3];
        float mean = ts * (1.0f / D_);
        float var  = tq * (1.0f / D_) - mean*mean;
        mv[0] = mean; mv[1] = rsqrtf(var + 1e-5f);
    }
    __syncthreads();
    float mean = mv[0], rstd = mv[1];
    float4 wv = ((const float4*)w)[tid];
    float4 bv = ((const float4*)b)[tid];
    float4 o;
    o.x = (v.x-mean)*rstd*wv.x + bv.x;
    o.y = (v.y-mean)*rstd*wv.y + bv.y;
    o.z = (v.z-mean)*rstd*wv.z + bv.z;
    o.w = (v.w-mean)*rstd*wv.w + bv.w;
    ((float4*)(out + (size_t)row * D_))[tid] = o;
}

__global__ __launch_bounds__(256) void rope_kernel(float* __restrict__ qkv)
{
    int gid = blockIdx.x * 256 + threadIdx.x;
    int t = gid >> 9;
    int r = gid & 511;
    int h = r >> 5;
    int d = r & 31;
    float inv = powf(10000.0f, -(float)d * (1.0f/32.0f));
    float fr = (float)t * inv;
    float s, c;
    sincosf(fr, &s, &c);
    float* base = qkv + (size_t)t*D3_ + h*HD_ + d;
    float q1 = base[0], q2 = base[32];
    base[0]  = q1*c - q2*s;
    base[32] = q1*s + q2*c;
    float* kb = base + D_;
    float k1 = kb[0], k2 = kb[32];
    kb[0]  = k1*c - k2*s;
    kb[32] = k1*s + k2*c;
}

__global__ __launch_bounds__(256) void ln2_gate_kernel(
    const float* __restrict__ x2, const float* __restrict__ w,
    const float* __restrict__ b, const float* __restrict__ gwm,
    const float* __restrict__ gbv, float* __restrict__ h2,
    int* __restrict__ gi, float* __restrict__ gw)
{
    const int row = blockIdx.x, tid = threadIdx.x;
    const int lane = tid & 63, wave = tid >> 6;
    float4 v = ((const float4*)(x2 + (size_t)row * D_))[tid];
    float s  = v.x + v.y + v.z + v.w;
    float sq = v.x*v.x + v.y*v.y + v.z*v.z + v.w*v.w;
    #pragma unroll
    for (int off = 32; off; off >>= 1) {
        s  += __shfl_down(s, off);
        sq += __shfl_down(sq, off);
    }
    __shared__ float rs[4], rq[4], mv[2];
    if (lane == 0) { rs[wave] = s; rq[wave] = sq; }
    __syncthreads();
    if (tid == 0) {
        float ts = rs[0]+rs[1]+rs[2]+rs[3];
        float tq = rq[0]+rq[1]+rq[2]+rq[3];
        float mean = ts * (1.0f / D_);
        float var  = tq * (1.0f / D_) - mean*mean;
        mv[0] = mean; mv[1] = rsqrtf(var + 1e-5f);
    }
    __syncthreads();
    float mean = mv[0], rstd = mv[1];
    float4 wv = ((const float4*)w)[tid];
    float4 bv = ((const float4*)b)[tid];
    float hv[4];
    hv[0] = (v.x-mean)*rstd*wv.x + bv.x;
    hv[1] = (v.y-mean)*rstd*wv.y + bv.y;
    hv[2] = (v.z-mean)*rstd*wv.z + bv.z;
    hv[3] = (v.w-mean)*rstd*wv.w + bv.w;
    float4 o; o.x=hv[0]; o.y=hv[1]; o.z=hv[2]; o.w=hv[3];
    ((float4*)(h2 + (size_t)row * D_))[tid] = o;

    float acc[E_] = {};
    int c = tid * 4;
    #pragma unroll
    for (int j = 0; j < 4; j++) {
        const float* gr = gwm + (size_t)(c+j) * E_;
        #pragma unroll
        for (int e = 0; e < E_; e++) acc[e] += hv[j] * gr[e];
    }
    #pragma unroll
    for (int off = 32; off; off >>= 1)
        #pragma unroll
        for (int e = 0; e < E_; e++) acc[e] += __shfl_down(acc[e], off);
    __shared__ float gred[4][E_];
    if (lane == 0)
        for (int e = 0; e < E_; e++) gred[wave][e] = acc[e];
    __syncthreads();
    if (tid == 0) {
        float lg[E_];
        float mxl = -FLT_MAX; int mi = 0;
        for (int e = 0; e < E_; e++)
            lg[e] = gred[0][e]+gred[1][e]+gred[2][e]+gred[3][e] + gbv[e];
        for (int e = 0; e < E_; e++)
            if (lg[e] > mxl) { mxl = lg[e]; mi = e; }
        float ssum = 0.f;
        for (int e = 0; e < E_; e++) ssum += expf(lg[e] - mxl);
        gi[row] = mi;
        gw[row] = 1.0f / ssum;
    }
}

__global__ void route_kernel(const int* __restrict__ gi,
                             int* __restrict__ offs, int* __restrict__ perm)
{
    __shared__ int cnt[E_], c2[E_], off[E_+1];
    const int tid = threadIdx.x;
    if (tid < E_) { cnt[tid] = 0; c2[tid] = 0; }
    __syncthreads();
    int e = gi[tid];
    atomicAdd(&cnt[e], 1);
    __syncthreads();
    if (tid == 0) {
        off[0] = 0;
        for (int i = 0; i < E_; i++) off[i+1] = off[i] + cnt[i];
        for (int i = 0; i <= E_; i++) offs[i] = off[i];
    }
    __syncthreads();
    int r = atomicAdd(&c2[e], 1);
    perm[off[e] + r] = tid;
}

__global__ void loss_kernel(const int* __restrict__ gi,
                            const float* __restrict__ gw, float* __restrict__ out)
{
    __shared__ float ss[E_], sc[E_];
    const int tid = threadIdx.x;
    if (tid < E_) { ss[tid] = 0.f; sc[tid] = 0.f; }
    __syncthreads();
    for (int t = tid; t < T_; t += 256) {
        int e = gi[t];
        atomicAdd(&ss[e], gw[t]);
        atomicAdd(&sc[e], 1.0f);
    }
    __syncthreads();
    if (tid == 0) {
        float loss = 0.f;
        for (int e = 0; e < E_; e++) {
            float u = ss[e] / (sc[e] + 1e-8f);
            float d = u - 0.125f;
            loss += d * d;
        }
        out[(size_t)T_ * D_] = loss;
    }
}

extern "C" void kernel_launch(void* const* d_in, const int* in_sizes, int n_in,
                              void* d_out, int out_size, void* d_ws, size_t ws_size,
                              hipStream_t stream)
{
    const float* x     = (const float*)d_in[0];
    const int*   ids   = (const int*)d_in[1];
    const float* ln1w  = (const float*)d_in[2];
    const float* ln1b  = (const float*)d_in[3];
    const float* qkvw  = (const float*)d_in[4];
    const float* qkvb  = (const float*)d_in[5];
    const float* aow   = (const float*)d_in[6];
    const float* aob   = (const float*)d_in[7];
    const float* ln2w  = (const float*)d_in[8];
    const float* ln2b  = (const float*)d_in[9];
    const float* gatew = (const float*)d_in[10];
    const float* gateb = (const float*)d_in[11];
    const float* fcw   = (const float*)d_in[12];
    const float* fcb   = (const float*)d_in[13];
    const float* eoutw = (const float*)d_in[14];
    const float* eoutb = (const float*)d_in[15];
    float* out = (float*)d_out;
    float* ws  = (float*)d_ws;

    float* h    = ws + WS_H;      // LN1 out; later attn sacc; later partials
    float* sacc = ws + WS_H;
    float* part = ws + WS_PART;   // 4 x T*D partials (overlaps h/qkv region)
    float* qkv  = ws + WS_QKV;
    float* attn = ws + WS_ATTN;
    float* x2   = ws + WS_X2;
    float* h2   = ws + WS_H2;
    float* abuf = ws + WS_A;
    float* gw   = ws + WS_GW;
    int*   gi   = (int*)(ws + WS_GI);
    int*   offs = (int*)(ws + WS_OFFS);
    int*   perm = (int*)(ws + WS_PERM);

    // 1. LN1
    ln_kernel<<<T_, 256, 0, stream>>>(x, ln1w, ln1b, h);
    // 2. QKV projection (swapped-operand: weights streamed coalesced)
    qkv_sw<<<dim3(8, 48), 256, 0, stream>>>(h, qkvw, qkvb, qkv);
    // 3. RoPE
    rope_kernel<<<(T_*H_*32)/256, 256, 0, stream>>>(qkv);
    // 4. MFMA flash attention
    flash_attn<<<dim3(T_/32, H_), 128, 0, stream>>>(qkv, ids, attn);
    // 5. zero attn split-K accumulator (h dead)
    hipMemsetAsync(sacc, 0, (size_t)T_*D_*sizeof(float), stream);
    // 6. attn output projection (MFMA, split-K=4, atomic)
    gemm_mfma_acc<<<dim3(D_/64, T_/128, 4), 256, 0, stream>>>(
        attn, D_, aow, D_, sacc, D_, D_, 4);
    // 7. residual + bias
    ep_attn<<<T_, 256, 0, stream>>>(x, sacc, aob, x2);
    // 8. LN2 + gate
    ln2_gate_kernel<<<T_, 256, 0, stream>>>(x2, ln2w, ln2b, gatew, gateb, h2, gi, gw);
    // 9. routing
    route_kernel<<<1, T_, 0, stream>>>(gi, offs, perm);
    // 10. expert fc + GLU (swapped-operand, coalesced weight streaming)
    moe_fc_sw<<<dim3(8, F_/64, E_), 256, 0, stream>>>(h2, fcw, fcb, offs, perm, abuf);
    // 11. expert out (swapped, split-K=4 -> disjoint partials, no atomics;
    //     qkv buffer is dead, partials overlay WS_H+WS_QKV)
    moe_out_sw<<<dim3(8, D_/64, 4*E_), 256, 0, stream>>>(abuf, eoutw, offs, perm, part);
    // 12. residual + gate scale + bias + partial reduction
    ep_moe2<<<T_, 256, 0, stream>>>(x2, part, eoutb, gw, gi, out);
    // 13. aux loss
    loss_kernel<<<1, 256, 0, stream>>>(gi, gw, out);
}

// Round 6
// 643.048 us; speedup vs baseline: 2.0376x; 2.0376x over previous
//
#include <hip/hip_runtime.h>
#include <float.h>
#include <math.h>
#include <stdint.h>

#define T_ 1024
#define D_ 1024
#define H_ 16
#define HD_ 64
#define E_ 8
#define F_ 2560
#define D3_ 3072
#define F2_ 5120

// ---- workspace layout (float offsets) ----
#define WS_H    0u         // 1M   LN1 out / attn sacc / moe partials[0..3]
#define WS_QKV  1048576u   // 3M   qkv (T,3D)
#define WS_ATTN 4194304u   // 1M   attention out (T,D)
#define WS_X2   5242880u   // 1M   x + attn proj (T,D)
#define WS_H2   6291456u   // 1M   LN2 out
#define WS_A    7340032u   // 2.62M gated activation (T,F)
#define WS_GW   9961472u
#define WS_GI   9962496u
#define WS_OFFS 9963520u
#define WS_PERM 9963536u
#define WS_PART 0u         // 4 * T_*D_ floats = 16 MB (overlays WS_H+WS_QKV, dead then)

typedef short short8 __attribute__((ext_vector_type(8)));
typedef __bf16 bf16x8 __attribute__((ext_vector_type(8)));
typedef float floatx4 __attribute__((ext_vector_type(4)));

union FragU { short8 s; bf16x8 b; };

__device__ __forceinline__ short f2bf(float f) {
    union { float f; uint32_t u; } a; a.f = f;
    uint32_t r = a.u + 0x7fffu + ((a.u >> 16) & 1u);
    return (short)(r >> 16);
}

__device__ __forceinline__ void cvt16(const float4& a0, const float4& a1,
                                      const float4& a2, const float4& a3,
                                      short8& c0, short8& c1) {
    c0[0]=f2bf(a0.x); c0[1]=f2bf(a0.y); c0[2]=f2bf(a0.z); c0[3]=f2bf(a0.w);
    c0[4]=f2bf(a1.x); c0[5]=f2bf(a1.y); c0[6]=f2bf(a1.z); c0[7]=f2bf(a1.w);
    c1[0]=f2bf(a2.x); c1[1]=f2bf(a2.y); c1[2]=f2bf(a2.z); c1[3]=f2bf(a2.w);
    c1[4]=f2bf(a3.x); c1[5]=f2bf(a3.y); c1[6]=f2bf(a3.z); c1[7]=f2bf(a3.w);
}

// =====================================================================
// Wide-BN GEMM core pieces (BM=128 tokens, BN=256 weight cols, BK=32).
// B global loads: one full k-row slice per wave-instruction (512B-1KB runs).
// B LDS: n-major stride 40 bf16, k XOR-swizzled by ((n>>2)&3)<<3 to spread
// banks on the packed-b32 transpose writes. A LDS: plain [m][k] stride 40.
// Wave grid 2x2: wm = token half (64), wn = col half (128).
// =====================================================================

#define W_IDS \
    const int tid = threadIdx.x;                   \
    const int lane = tid & 63, wv = tid >> 6;      \
    const int wm = wv & 1, wn = wv >> 1;           \
    const int quad = lane >> 4, lm = lane & 15;    \
    const int am = tid >> 1, akh = (tid & 1) * 16;

// stage A regs -> LDS (plain layout)
#define A_STORE(AP, AR) {                                          \
    short8 s0, s1;                                                 \
    if (AP) cvt16(AR[0], AR[1], AR[2], AR[3], s0, s1);             \
    else { s0 = (short8){0,0,0,0,0,0,0,0}; s1 = s0; }              \
    *(short8*)&As[am*40 + akh]     = s0;                           \
    *(short8*)&As[am*40 + akh + 8] = s1; }

// stage B regs -> LDS (swizzled transpose, packed k-pairs)
#define B_STORE(BR) {                                              \
    uint32_t* Bu = (uint32_t*)Bs;                                  \
    _Pragma("unroll")                                              \
    for (int s = 0; s < 4; s++) {                                  \
        int r0 = s*8 + wv*2;                                       \
        _Pragma("unroll")                                          \
        for (int i = 0; i < 4; i++) {                              \
            uint32_t pk = (uint32_t)(unsigned short)f2bf(((const float*)&BR[2*s])[i]) \
                 | ((uint32_t)(unsigned short)f2bf(((const float*)&BR[2*s+1])[i]) << 16); \
            Bu[(4*lane + i)*20 + ((r0 >> 1) ^ ((lane & 3) << 2))] = pk; \
        } } }

#define B_LOAD(BR, BP, ROWOFF, LDB) {                              \
    _Pragma("unroll")                                              \
    for (int s = 0; s < 4; s++) {                                  \
        int r0 = s*8 + wv*2;                                       \
        BR[2*s]   = *(const float4*)(BP + (size_t)(ROWOFF + r0) * LDB);     \
        BR[2*s+1] = *(const float4*)(BP + (size_t)(ROWOFF + r0 + 1) * LDB); \
    } }

#define A_LOAD(AR, AP, KOFF) {                                     \
    if (AP) { _Pragma("unroll")                                    \
        for (int i = 0; i < 4; i++) AR[i] = *(const float4*)(AP + (KOFF) + i*4); } }

// ---- qkv projection: qkv = h @ qkvw + qkvb ----
__global__ __launch_bounds__(256, 2) void qkv_w(
    const float* __restrict__ h, const float* __restrict__ qkvw,
    const float* __restrict__ qkvb, float* __restrict__ qkv)
{
    const int col0 = blockIdx.x * 256;
    const int y0 = blockIdx.y * 128;
    __shared__ __align__(16) short As[128*40];
    __shared__ __align__(16) short Bs[256*40];
    W_IDS

    floatx4 acc[4][8];
    #pragma unroll
    for (int i=0;i<4;i++)
        #pragma unroll
        for (int j=0;j<8;j++) acc[i][j] = (floatx4){0.f,0.f,0.f,0.f};

    const float* ap = h + (size_t)(y0 + am)*D_ + akh;
    const float* bp = qkvw + col0 + 4*lane;

    float4 aR[4], bR[8];
    A_LOAD(aR, ap, 0)
    B_LOAD(bR, bp, 0, D3_)

    for (int k0 = 0; k0 < D_; k0 += 32) {
        __syncthreads();
        A_STORE(ap, aR)
        B_STORE(bR)
        __syncthreads();
        if (k0 + 32 < D_) {
            A_LOAD(aR, ap, k0 + 32)
            B_LOAD(bR, bp, k0 + 32, D3_)
        }
        FragU fa[4], fb[8];
        #pragma unroll
        for (int i=0;i<4;i++) fa[i].s = *(short8*)&As[(wm*64 + i*16 + lm)*40 + quad*8];
        const int kk = (quad*8) ^ (((lm>>2)&3)<<3);
        #pragma unroll
        for (int j=0;j<8;j++) fb[j].s = *(short8*)&Bs[(wn*128 + j*16 + lm)*40 + kk];
        #pragma unroll
        for (int i=0;i<4;i++)
            #pragma unroll
            for (int j=0;j<8;j++)
                acc[i][j] = __builtin_amdgcn_mfma_f32_16x16x32_bf16(fa[i].b, fb[j].b, acc[i][j], 0,0,0);
    }
    #pragma unroll
    for (int j=0;j<8;j++) {
        int col = col0 + wn*128 + j*16 + lm;
        float bb = qkvb[col];
        #pragma unroll
        for (int i=0;i<4;i++)
            #pragma unroll
            for (int r=0;r<4;r++) {
                int tok = y0 + wm*64 + i*16 + quad*4 + r;
                qkv[(size_t)tok*D3_ + col] = acc[i][j][r] + bb;
            }
    }
}

// ---- MoE fc + GLU (routed). j 0..3 = x1 cols, j 4..7 = x2 cols (same n). ----
__global__ __launch_bounds__(256, 2) void moe_fc_w(
    const float* __restrict__ h2, const float* __restrict__ fcw,
    const float* __restrict__ fcb, const int* __restrict__ offs,
    const int* __restrict__ perm, float* __restrict__ aout)
{
    const int e = blockIdx.z;
    const int off = offs[e], Ne = offs[e+1] - off;
    const int y0 = blockIdx.y * 128;
    if (y0 >= Ne) return;
    const int col0 = blockIdx.x * 128;   // gated output col tile

    __shared__ __align__(16) short As[128*40];
    __shared__ __align__(16) short Bs[256*40];
    __shared__ int toks[128];
    W_IDS
    if (tid < 128) {
        int r = y0 + tid;
        toks[tid] = (r < Ne) ? perm[off + r] : -1;
    }
    __syncthreads();

    floatx4 acc[4][8];
    #pragma unroll
    for (int i=0;i<4;i++)
        #pragma unroll
        for (int j=0;j<8;j++) acc[i][j] = (floatx4){0.f,0.f,0.f,0.f};

    const int tokA = toks[am];
    const float* ap = (tokA >= 0) ? (h2 + (size_t)tokA*D_ + akh) : nullptr;
    // lanes 0-31: x1 run (512B); lanes 32-63: x2 run (512B)
    const int gcol = (lane < 32) ? (col0 + 4*lane) : (F_ + col0 + 4*lane - 128);
    const float* bp = fcw + (size_t)e*D_*F2_ + gcol;

    float4 aR[4] = {}, bR[8];
    A_LOAD(aR, ap, 0)
    B_LOAD(bR, bp, 0, F2_)

    for (int k0 = 0; k0 < D_; k0 += 32) {
        __syncthreads();
        A_STORE(ap, aR)
        B_STORE(bR)
        __syncthreads();
        if (k0 + 32 < D_) {
            A_LOAD(aR, ap, k0 + 32)
            B_LOAD(bR, bp, k0 + 32, F2_)
        }
        FragU fa[4], fb[8];
        #pragma unroll
        for (int i=0;i<4;i++) fa[i].s = *(short8*)&As[(wm*64 + i*16 + lm)*40 + quad*8];
        const int kk = (quad*8) ^ (((lm>>2)&3)<<3);
        #pragma unroll
        for (int j=0;j<4;j++) {
            fb[j].s   = *(short8*)&Bs[(wn*64 + j*16 + lm)*40 + kk];          // x1
            fb[j+4].s = *(short8*)&Bs[(128 + wn*64 + j*16 + lm)*40 + kk];    // x2
        }
        #pragma unroll
        for (int i=0;i<4;i++)
            #pragma unroll
            for (int j=0;j<8;j++)
                acc[i][j] = __builtin_amdgcn_mfma_f32_16x16x32_bf16(fa[i].b, fb[j].b, acc[i][j], 0,0,0);
    }
    #pragma unroll
    for (int j=0;j<4;j++) {
        int col = col0 + wn*64 + j*16 + lm;
        float b1 = fcb[(size_t)e*F2_ + col];
        float b2 = fcb[(size_t)e*F2_ + F_ + col];
        #pragma unroll
        for (int i=0;i<4;i++)
            #pragma unroll
            for (int r=0;r<4;r++) {
                int tk = toks[wm*64 + i*16 + quad*4 + r];
                if (tk < 0) continue;
                float v1 = acc[i][j][r] + b1;
                float v2 = acc[i][j+4][r] + b2;
                float g = v2 * 0.5f * (1.0f + erff(v2 * 0.70710678118654752f));
                aout[(size_t)tk*F_ + col] = v1 * g;
            }
    }
}

// ---- MoE out (routed, split-K=4 -> disjoint partials) ----
__global__ __launch_bounds__(256, 2) void moe_out_w(
    const float* __restrict__ abuf, const float* __restrict__ ew,
    const int* __restrict__ offs, const int* __restrict__ perm,
    float* __restrict__ part)
{
    const int e  = blockIdx.z >> 2;
    const int sk = blockIdx.z & 3;
    const int off = offs[e], Ne = offs[e+1] - off;
    const int y0 = blockIdx.y * 128;
    if (y0 >= Ne) return;
    const int col0 = blockIdx.x * 256;

    __shared__ __align__(16) short As[128*40];
    __shared__ __align__(16) short Bs[256*40];
    __shared__ int toks[128];
    W_IDS
    if (tid < 128) {
        int r = y0 + tid;
        toks[tid] = (r < Ne) ? perm[off + r] : -1;
    }
    __syncthreads();

    floatx4 acc[4][8];
    #pragma unroll
    for (int i=0;i<4;i++)
        #pragma unroll
        for (int j=0;j<8;j++) acc[i][j] = (floatx4){0.f,0.f,0.f,0.f};

    const int tokA = toks[am];
    const float* ap = (tokA >= 0) ? (abuf + (size_t)tokA*F_ + akh) : nullptr;
    const float* bp = ew + (size_t)e*F_*D_ + col0 + 4*lane;
    const int koff = sk * (F_/4), kend = koff + (F_/4);   // 640 per chunk

    float4 aR[4] = {}, bR[8];
    A_LOAD(aR, ap, koff)
    B_LOAD(bR, bp, koff, D_)

    for (int k0 = koff; k0 < kend; k0 += 32) {
        __syncthreads();
        A_STORE(ap, aR)
        B_STORE(bR)
        __syncthreads();
        if (k0 + 32 < kend) {
            A_LOAD(aR, ap, k0 + 32)
            B_LOAD(bR, bp, k0 + 32, D_)
        }
        FragU fa[4], fb[8];
        #pragma unroll
        for (int i=0;i<4;i++) fa[i].s = *(short8*)&As[(wm*64 + i*16 + lm)*40 + quad*8];
        const int kk = (quad*8) ^ (((lm>>2)&3)<<3);
        #pragma unroll
        for (int j=0;j<8;j++) fb[j].s = *(short8*)&Bs[(wn*128 + j*16 + lm)*40 + kk];
        #pragma unroll
        for (int i=0;i<4;i++)
            #pragma unroll
            for (int j=0;j<8;j++)
                acc[i][j] = __builtin_amdgcn_mfma_f32_16x16x32_bf16(fa[i].b, fb[j].b, acc[i][j], 0,0,0);
    }
    float* pb = part + (size_t)sk*T_*D_;
    #pragma unroll
    for (int j=0;j<8;j++) {
        int col = col0 + wn*128 + j*16 + lm;
        #pragma unroll
        for (int i=0;i<4;i++)
            #pragma unroll
            for (int r=0;r<4;r++) {
                int tk = toks[wm*64 + i*16 + quad*4 + r];
                if (tk >= 0) pb[(size_t)tk*D_ + col] = acc[i][j][r];
            }
    }
}

// ===================== attn-out projection (R4 kernel, kept) =====================
#define GEMM_IDS \
    const int tid  = threadIdx.x;                 \
    const int a_m  = tid >> 1;                    \
    const int a_kh = (tid & 1) * 16;              \
    const int lane = tid & 63, wave = tid >> 6;   \
    const int wm = wave & 1,  wn = wave >> 1;     \
    const int quad = lane >> 4, lm = lane & 15;

__global__ __launch_bounds__(256) void gemm_mfma_acc(
    const float* __restrict__ A, int lda,
    const float* __restrict__ B, int ldb,
    float* __restrict__ Cacc, int ldc, int K, int nsk)
{
    const int sk = blockIdx.z;
    const int row0 = blockIdx.y * 128;
    const int col0 = blockIdx.x * 64;

    __shared__ __align__(16) short As[4*128*8];
    __shared__ __align__(16) short Bs[64*40];
    GEMM_IDS
    const int b_n = tid >> 2, b_kc = tid & 3;

    floatx4 acc[4][2];
    #pragma unroll
    for (int i=0;i<4;i++)
        #pragma unroll
        for (int j=0;j<2;j++) acc[i][j] = (floatx4){0.f,0.f,0.f,0.f};

    const float* apx = A + (size_t)(row0 + a_m) * lda + a_kh;
    const float* bpx = B + (size_t)(b_kc*8) * ldb + col0 + b_n;
    const int kcA = (tid & 1) * 2;
    const int Kp = K / nsk;
    const int koff = sk * Kp, kend = koff + Kp;

    float4 a0, a1, a2, a3; float bvv[8];
    a0 = *(const float4*)(apx + koff);     a1 = *(const float4*)(apx + koff + 4);
    a2 = *(const float4*)(apx + koff + 8); a3 = *(const float4*)(apx + koff + 12);
    {
        const float* bp2 = bpx + (size_t)koff * ldb;
        #pragma unroll
        for (int j=0;j<8;j++) bvv[j] = bp2[(size_t)j*ldb];
    }

    for (int k0 = koff; k0 < kend; k0 += 32) {
        __syncthreads();
        short8 c0, c1, cb;
        cvt16(a0,a1,a2,a3,c0,c1);
        #pragma unroll
        for (int j=0;j<8;j++) cb[j] = f2bf(bvv[j]);
        *(short8*)&As[((kcA  )*128 + a_m)*8] = c0;
        *(short8*)&As[((kcA+1)*128 + a_m)*8] = c1;
        *(short8*)&Bs[b_n*40 + b_kc*8] = cb;
        __syncthreads();
        if (k0 + 32 < kend) {
            const float* ap2 = apx + k0 + 32;
            a0 = *(const float4*)(ap2);     a1 = *(const float4*)(ap2 + 4);
            a2 = *(const float4*)(ap2 + 8); a3 = *(const float4*)(ap2 + 12);
            const float* bp2 = bpx + (size_t)(k0+32) * ldb;
            #pragma unroll
            for (int j=0;j<8;j++) bvv[j] = bp2[(size_t)j*ldb];
        }
        FragU fa[4], fb[2];
        #pragma unroll
        for (int i=0;i<4;i++) fa[i].s = *(short8*)&As[(quad*128 + wm*64 + i*16 + lm)*8];
        #pragma unroll
        for (int j=0;j<2;j++) fb[j].s = *(short8*)&Bs[(wn*32 + j*16 + lm)*40 + quad*8];
        #pragma unroll
        for (int i=0;i<4;i++)
            #pragma unroll
            for (int j=0;j<2;j++)
                acc[i][j] = __builtin_amdgcn_mfma_f32_16x16x32_bf16(fa[i].b, fb[j].b, acc[i][j], 0,0,0);
    }
    #pragma unroll
    for (int i=0;i<4;i++)
        #pragma unroll
        for (int j=0;j<2;j++) {
            int col = col0 + wn*32 + j*16 + lm;
            #pragma unroll
            for (int r=0;r<4;r++) {
                int row = row0 + wm*64 + i*16 + quad*4 + r;
                atomicAdd(&Cacc[(size_t)row*ldc + col], acc[i][j][r]);
            }
        }
}

// ===================== MFMA flash attention (unchanged) =====================
__global__ __launch_bounds__(128) void flash_attn(
    const float* __restrict__ qkv, const int* __restrict__ ids,
    float* __restrict__ attnout)
{
    const int h  = blockIdx.y;
    const int q0 = blockIdx.x * 32;
    const int tid = threadIdx.x;
    const int lane = tid & 63, w = tid >> 6;
    const int quad = lane >> 4, lm = lane & 15;

    __shared__ __align__(16) short Qs[32*72];
    __shared__ __align__(16) short Ks[64*72];
    __shared__ __align__(16) short Vt[64*72];
    __shared__ __align__(16) short Ps[2][16*72];
    __shared__ int globf[32];

    {
        int row = tid >> 2, c = (tid & 3) * 16;
        const float* qp = qkv + (size_t)(q0 + row) * D3_ + h * HD_ + c;
        float4 f0 = *(const float4*)(qp);
        float4 f1 = *(const float4*)(qp + 4);
        float4 f2 = *(const float4*)(qp + 8);
        float4 f3 = *(const float4*)(qp + 12);
        short8 s0, s1;
        cvt16(f0, f1, f2, f3, s0, s1);
        *(short8*)&Qs[row*72 + c]     = s0;
        *(short8*)&Qs[row*72 + c + 8] = s1;
    }
    if (tid < 32) {
        int id = ids[q0 + tid];
        globf[tid] = (id >= 2 && id <= 7) ? 1 : 0;
    }
    __syncthreads();

    FragU QA[2];
    #pragma unroll
    for (int s = 0; s < 2; s++)
        QA[s].s = *(short8*)&Qs[(w*16 + lm)*72 + s*32 + quad*8];

    int any = 0;
    #pragma unroll
    for (int i = 0; i < 32; i++) any |= globf[i];
    const int nt = any ? (T_/64) : ((q0 + 31) >> 6) + 1;

    int gq[4]; int qidx[4];
    #pragma unroll
    for (int r = 0; r < 4; r++) {
        int ql = w*16 + quad*4 + r;
        qidx[r] = q0 + ql;
        gq[r] = globf[ql];
    }

    float mrow[4] = {-1e30f, -1e30f, -1e30f, -1e30f};
    float lrow[4] = {0.f, 0.f, 0.f, 0.f};
    floatx4 Oacc[4];
    #pragma unroll
    for (int n = 0; n < 4; n++) Oacc[n] = (floatx4){0.f, 0.f, 0.f, 0.f};

    for (int kt = 0; kt < nt; kt++) {
        __syncthreads();
        #pragma unroll
        for (int rep = 0; rep < 2; rep++) {
            int key = (tid >> 2) + rep*32;
            int c = (tid & 3) * 16;
            const float* kp = qkv + (size_t)(kt*64 + key) * D3_ + D_ + h*HD_ + c;
            float4 f0 = *(const float4*)(kp);
            float4 f1 = *(const float4*)(kp + 4);
            float4 f2 = *(const float4*)(kp + 8);
            float4 f3 = *(const float4*)(kp + 12);
            short8 s0, s1;
            cvt16(f0, f1, f2, f3, s0, s1);
            *(short8*)&Ks[key*72 + c]     = s0;
            *(short8*)&Ks[key*72 + c + 8] = s1;
        }
        #pragma unroll
        for (int rep = 0; rep < 8; rep++) {
            int lin = tid + rep*128;
            int key = lin >> 4;
            int c = (lin & 15) * 4;
            const float* vp = qkv + (size_t)(kt*64 + key) * D3_ + 2*D_ + h*HD_ + c;
            float4 f = *(const float4*)vp;
            Vt[(c+0)*72 + key] = f2bf(f.x);
            Vt[(c+1)*72 + key] = f2bf(f.y);
            Vt[(c+2)*72 + key] = f2bf(f.z);
            Vt[(c+3)*72 + key] = f2bf(f.w);
        }
        __syncthreads();

        floatx4 Sv[4];
        #pragma unroll
        for (int n = 0; n < 4; n++) {
            Sv[n] = (floatx4){0.f, 0.f, 0.f, 0.f};
            #pragma unroll
            for (int s = 0; s < 2; s++) {
                FragU KB;
                KB.s = *(short8*)&Ks[(n*16 + lm)*72 + s*32 + quad*8];
                Sv[n] = __builtin_amdgcn_mfma_f32_16x16x32_bf16(QA[s].b, KB.b, Sv[n], 0, 0, 0);
            }
        }
        #pragma unroll
        for (int n = 0; n < 4; n++) {
            int key = kt*64 + n*16 + lm;
            #pragma unroll
            for (int r = 0; r < 4; r++) {
                float v = Sv[n][r] * 0.125f;
                if (!gq[r] && key > qidx[r]) v = -1e30f;
                Sv[n][r] = v;
            }
        }
        float mnew[4], alpha[4], tsum[4];
        #pragma unroll
        for (int r = 0; r < 4; r++) {
            float tm = fmaxf(fmaxf(Sv[0][r], Sv[1][r]), fmaxf(Sv[2][r], Sv[3][r]));
            #pragma unroll
            for (int x = 1; x < 16; x <<= 1) tm = fmaxf(tm, __shfl_xor(tm, x));
            mnew[r] = fmaxf(mrow[r], tm);
            alpha[r] = __expf(mrow[r] - mnew[r]);
            mrow[r] = mnew[r];
            tsum[r] = 0.f;
        }
        #pragma unroll
        for (int n = 0; n < 4; n++) {
            #pragma unroll
            for (int r = 0; r < 4; r++) {
                float p = __expf(Sv[n][r] - mnew[r]);
                tsum[r] += p;
                Ps[w][(quad*4 + r)*72 + n*16 + lm] = f2bf(p);
            }
        }
        #pragma unroll
        for (int r = 0; r < 4; r++) {
            #pragma unroll
            for (int x = 1; x < 16; x <<= 1) tsum[r] += __shfl_xor(tsum[r], x);
            lrow[r] = lrow[r] * alpha[r] + tsum[r];
        }
        #pragma unroll
        for (int n = 0; n < 4; n++)
            #pragma unroll
            for (int r = 0; r < 4; r++) Oacc[n][r] *= alpha[r];

        #pragma unroll
        for (int s = 0; s < 2; s++) {
            FragU PA;
            PA.s = *(short8*)&Ps[w][lm*72 + s*32 + quad*8];
            #pragma unroll
            for (int n = 0; n < 4; n++) {
                FragU VB;
                VB.s = *(short8*)&Vt[(n*16 + lm)*72 + s*32 + quad*8];
                Oacc[n] = __builtin_amdgcn_mfma_f32_16x16x32_bf16(PA.b, VB.b, Oacc[n], 0, 0, 0);
            }
        }
    }

    #pragma unroll
    for (int n = 0; n < 4; n++)
        #pragma unroll
        for (int r = 0; r < 4; r++) {
            float o = Oacc[n][r] / lrow[r];
            attnout[(size_t)qidx[r]*D_ + h*HD_ + n*16 + lm] = o;
        }
}

// ===================== epilogues =====================
__global__ __launch_bounds__(256) void ep_attn(
    const float* __restrict__ x, const float* __restrict__ sacc,
    const float* __restrict__ aob, float* __restrict__ x2)
{
    int row = blockIdx.x, tid = threadIdx.x;
    float4 xv = ((const float4*)(x + (size_t)row*D_))[tid];
    float4 sv = ((const float4*)(sacc + (size_t)row*D_))[tid];
    float4 bv = ((const float4*)aob)[tid];
    float4 o;
    o.x = xv.x + sv.x + bv.x; o.y = xv.y + sv.y + bv.y;
    o.z = xv.z + sv.z + bv.z; o.w = xv.w + sv.w + bv.w;
    ((float4*)(x2 + (size_t)row*D_))[tid] = o;
}

__global__ __launch_bounds__(256) void ep_moe2(
    const float* __restrict__ x2, const float* __restrict__ part,
    const float* __restrict__ eob, const float* __restrict__ gw,
    const int* __restrict__ gi, float* __restrict__ out)
{
    int row = blockIdx.x, tid = threadIdx.x;
    float g = gw[row];
    int e = gi[row];
    float4 xv = ((const float4*)(x2 + (size_t)row*D_))[tid];
    float4 s0 = ((const float4*)(part + 0ul*T_*D_ + (size_t)row*D_))[tid];
    float4 s1 = ((const float4*)(part + 1ul*T_*D_ + (size_t)row*D_))[tid];
    float4 s2 = ((const float4*)(part + 2ul*T_*D_ + (size_t)row*D_))[tid];
    float4 s3 = ((const float4*)(part + 3ul*T_*D_ + (size_t)row*D_))[tid];
    float4 bv = ((const float4*)(eob + (size_t)e*D_))[tid];
    float4 o;
    o.x = xv.x + g*(s0.x+s1.x+s2.x+s3.x + bv.x);
    o.y = xv.y + g*(s0.y+s1.y+s2.y+s3.y + bv.y);
    o.z = xv.z + g*(s0.z+s1.z+s2.z+s3.z + bv.z);
    o.w = xv.w + g*(s0.w+s1.w+s2.w+s3.w + bv.w);
    ((float4*)(out + (size_t)row*D_))[tid] = o;
}

// ===================== small kernels =====================
__global__ __launch_bounds__(256) void ln_kernel(
    const float* __restrict__ x, const float* __restrict__ w,
    const float* __restrict__ b, float* __restrict__ out)
{
    const int row = blockIdx.x, tid = threadIdx.x;
    const int lane = tid & 63, wave = tid >> 6;
    float4 v = ((const float4*)(x + (size_t)row * D_))[tid];
    float s  = v.x + v.y + v.z + v.w;
    float sq = v.x*v.x + v.y*v.y + v.z*v.z + v.w*v.w;
    #pragma unroll
    for (int off = 32; off; off >>= 1) {
        s  += __shfl_down(s, off);
        sq += __shfl_down(sq, off);
    }
    __shared__ float rs[4], rq[4], mv[2];
    if (lane == 0) { rs[wave] = s; rq[wave] = sq; }
    __syncthreads();
    if (tid == 0) {
        float ts = rs[0]+rs[1]+rs[2]+rs[3];
        float tq = rq[0]+rq[1]+rq[2]+rq[3];
        float mean = ts * (1.0f / D_);
        float var  = tq * (1.0f / D_) - mean*mean;
        mv[0] = mean; mv[1] = rsqrtf(var + 1e-5f);
    }
    __syncthreads();
    float mean = mv[0], rstd = mv[1];
    float4 wv = ((const float4*)w)[tid];
    float4 bv = ((const float4*)b)[tid];
    float4 o;
    o.x = (v.x-mean)*rstd*wv.x + bv.x;
    o.y = (v.y-mean)*rstd*wv.y + bv.y;
    o.z = (v.z-mean)*rstd*wv.z + bv.z;
    o.w = (v.w-mean)*rstd*wv.w + bv.w;
    ((float4*)(out + (size_t)row * D_))[tid] = o;
}

__global__ __launch_bounds__(256) void rope_kernel(float* __restrict__ qkv)
{
    int gid = blockIdx.x * 256 + threadIdx.x;
    int t = gid >> 9;
    int r = gid & 511;
    int h = r >> 5;
    int d = r & 31;
    float inv = powf(10000.0f, -(float)d * (1.0f/32.0f));
    float fr = (float)t * inv;
    float s, c;
    sincosf(fr, &s, &c);
    float* base = qkv + (size_t)t*D3_ + h*HD_ + d;
    float q1 = base[0], q2 = base[32];
    base[0]  = q1*c - q2*s;
    base[32] = q1*s + q2*c;
    float* kb = base + D_;
    float k1 = kb[0], k2 = kb[32];
    kb[0]  = k1*c - k2*s;
    kb[32] = k1*s + k2*c;
}

__global__ __launch_bounds__(256) void ln2_gate_kernel(
    const float* __restrict__ x2, const float* __restrict__ w,
    const float* __restrict__ b, const float* __restrict__ gwm,
    const float* __restrict__ gbv, float* __restrict__ h2,
    int* __restrict__ gi, float* __restrict__ gw)
{
    const int row = blockIdx.x, tid = threadIdx.x;
    const int lane = tid & 63, wave = tid >> 6;
    float4 v = ((const float4*)(x2 + (size_t)row * D_))[tid];
    float s  = v.x + v.y + v.z + v.w;
    float sq = v.x*v.x + v.y*v.y + v.z*v.z + v.w*v.w;
    #pragma unroll
    for (int off = 32; off; off >>= 1) {
        s  += __shfl_down(s, off);
        sq += __shfl_down(sq, off);
    }
    __shared__ float rs[4], rq[4], mv[2];
    if (lane == 0) { rs[wave] = s; rq[wave] = sq; }
    __syncthreads();
    if (tid == 0) {
        float ts = rs[0]+rs[1]+rs[2]+rs[3];
        float tq = rq[0]+rq[1]+rq[2]+rq[3];
        float mean = ts * (1.0f / D_);
        float var  = tq * (1.0f / D_) - mean*mean;
        mv[0] = mean; mv[1] = rsqrtf(var + 1e-5f);
    }
    __syncthreads();
    float mean = mv[0], rstd = mv[1];
    float4 wv = ((const float4*)w)[tid];
    float4 bv = ((const float4*)b)[tid];
    float hv[4];
    hv[0] = (v.x-mean)*rstd*wv.x + bv.x;
    hv[1] = (v.y-mean)*rstd*wv.y + bv.y;
    hv[2] = (v.z-mean)*rstd*wv.z + bv.z;
    hv[3] = (v.w-mean)*rstd*wv.w + bv.w;
    float4 o; o.x=hv[0]; o.y=hv[1]; o.z=hv[2]; o.w=hv[3];
    ((float4*)(h2 + (size_t)row * D_))[tid] = o;

    float acc[E_] = {};
    int c = tid * 4;
    #pragma unroll
    for (int j = 0; j < 4; j++) {
        const float* gr = gwm + (size_t)(c+j) * E_;
        #pragma unroll
        for (int e = 0; e < E_; e++) acc[e] += hv[j] * gr[e];
    }
    #pragma unroll
    for (int off = 32; off; off >>= 1)
        #pragma unroll
        for (int e = 0; e < E_; e++) acc[e] += __shfl_down(acc[e], off);
    __shared__ float gred[4][E_];
    if (lane == 0)
        for (int e = 0; e < E_; e++) gred[wave][e] = acc[e];
    __syncthreads();
    if (tid == 0) {
        float lg[E_];
        float mxl = -FLT_MAX; int mi = 0;
        for (int e = 0; e < E_; e++)
            lg[e] = gred[0][e]+gred[1][e]+gred[2][e]+gred[3][e] + gbv[e];
        for (int e = 0; e < E_; e++)
            if (lg[e] > mxl) { mxl = lg[e]; mi = e; }
        float ssum = 0.f;
        for (int e = 0; e < E_; e++) ssum += expf(lg[e] - mxl);
        gi[row] = mi;
        gw[row] = 1.0f / ssum;
    }
}

__global__ void route_kernel(const int* __restrict__ gi,
                             int* __restrict__ offs, int* __restrict__ perm)
{
    __shared__ int cnt[E_], c2[E_], off[E_+1];
    const int tid = threadIdx.x;
    if (tid < E_) { cnt[tid] = 0; c2[tid] = 0; }
    __syncthreads();
    int e = gi[tid];
    atomicAdd(&cnt[e], 1);
    __syncthreads();
    if (tid == 0) {
        off[0] = 0;
        for (int i = 0; i < E_; i++) off[i+1] = off[i] + cnt[i];
        for (int i = 0; i <= E_; i++) offs[i] = off[i];
    }
    __syncthreads();
    int r = atomicAdd(&c2[e], 1);
    perm[off[e] + r] = tid;
}

__global__ void loss_kernel(const int* __restrict__ gi,
                            const float* __restrict__ gw, float* __restrict__ out)
{
    __shared__ float ss[E_], sc[E_];
    const int tid = threadIdx.x;
    if (tid < E_) { ss[tid] = 0.f; sc[tid] = 0.f; }
    __syncthreads();
    for (int t = tid; t < T_; t += 256) {
        int e = gi[t];
        atomicAdd(&ss[e], gw[t]);
        atomicAdd(&sc[e], 1.0f);
    }
    __syncthreads();
    if (tid == 0) {
        float loss = 0.f;
        for (int e = 0; e < E_; e++) {
            float u = ss[e] / (sc[e] + 1e-8f);
            float d = u - 0.125f;
            loss += d * d;
        }
        out[(size_t)T_ * D_] = loss;
    }
}

extern "C" void kernel_launch(void* const* d_in, const int* in_sizes, int n_in,
                              void* d_out, int out_size, void* d_ws, size_t ws_size,
                              hipStream_t stream)
{
    const float* x     = (const float*)d_in[0];
    const int*   ids   = (const int*)d_in[1];
    const float* ln1w  = (const float*)d_in[2];
    const float* ln1b  = (const float*)d_in[3];
    const float* qkvw  = (const float*)d_in[4];
    const float* qkvb  = (const float*)d_in[5];
    const float* aow   = (const float*)d_in[6];
    const float* aob   = (const float*)d_in[7];
    const float* ln2w  = (const float*)d_in[8];
    const float* ln2b  = (const float*)d_in[9];
    const float* gatew = (const float*)d_in[10];
    const float* gateb = (const float*)d_in[11];
    const float* fcw   = (const float*)d_in[12];
    const float* fcb   = (const float*)d_in[13];
    const float* eoutw = (const float*)d_in[14];
    const float* eoutb = (const float*)d_in[15];
    float* out = (float*)d_out;
    float* ws  = (float*)d_ws;

    float* h    = ws + WS_H;
    float* sacc = ws + WS_H;
    float* part = ws + WS_PART;
    float* qkv  = ws + WS_QKV;
    float* attn = ws + WS_ATTN;
    float* x2   = ws + WS_X2;
    float* h2   = ws + WS_H2;
    float* abuf = ws + WS_A;
    float* gw   = ws + WS_GW;
    int*   gi   = (int*)(ws + WS_GI);
    int*   offs = (int*)(ws + WS_OFFS);
    int*   perm = (int*)(ws + WS_PERM);

    // 1. LN1
    ln_kernel<<<T_, 256, 0, stream>>>(x, ln1w, ln1b, h);
    // 2. QKV projection (wide-BN coalesced-weight GEMM)
    qkv_w<<<dim3(D3_/256, T_/128), 256, 0, stream>>>(h, qkvw, qkvb, qkv);
    // 3. RoPE
    rope_kernel<<<(T_*H_*32)/256, 256, 0, stream>>>(qkv);
    // 4. MFMA flash attention
    flash_attn<<<dim3(T_/32, H_), 128, 0, stream>>>(qkv, ids, attn);
    // 5. zero attn split-K accumulator (h dead)
    hipMemsetAsync(sacc, 0, (size_t)T_*D_*sizeof(float), stream);
    // 6. attn output projection (R4 split-K=4, atomic)
    gemm_mfma_acc<<<dim3(D_/64, T_/128, 4), 256, 0, stream>>>(
        attn, D_, aow, D_, sacc, D_, D_, 4);
    // 7. residual + bias
    ep_attn<<<T_, 256, 0, stream>>>(x, sacc, aob, x2);
    // 8. LN2 + gate
    ln2_gate_kernel<<<T_, 256, 0, stream>>>(x2, ln2w, ln2b, gatew, gateb, h2, gi, gw);
    // 9. routing
    route_kernel<<<1, T_, 0, stream>>>(gi, offs, perm);
    // 10. expert fc + GLU (wide-BN, 512B weight runs, fused GLU)
    moe_fc_w<<<dim3(F_/128, T_/128, E_), 256, 0, stream>>>(h2, fcw, fcb, offs, perm, abuf);
    // 11. expert out (wide-BN, 1KB weight runs, split-K=4 -> disjoint partials)
    moe_out_w<<<dim3(D_/256, T_/128, 4*E_), 256, 0, stream>>>(abuf, eoutw, offs, perm, part);
    // 12. residual + gate scale + bias + partial reduction
    ep_moe2<<<T_, 256, 0, stream>>>(x2, part, eoutb, gw, gi, out);
    // 13. aux loss
    loss_kernel<<<1, 256, 0, stream>>>(gi, gw, out);
}